// Round 5
// baseline (88.903 us; speedup 1.0000x reference)
//
#include <hip/hip_runtime.h>
#include <hip/hip_bf16.h>

// R5 CALIBRATION PROBE v2 — disjoint-address write mirror.
// out[b, c, m] = weight[idx[b, m], c]; output values identical to R2 kernel.
//
// R4's same-address double-store was absorbed by L2 (nt stores still
// allocate in L2 on gfx950; delta was -0.06 us) -> confounded. This probe
// mirrors the 64 MiB output stream into d_ws (disjoint addresses, cannot
// be L2-absorbed: 32 MiB aggregate L2), guarded on ws_size >= 64 MiB.
// Delta dur = 67 MB / achieved write BW:
//   +9-14 us, kernel absent from top-5  -> writes at ~6 TB/s -> R2 kernel
//       was already at the write roofline (restore + <<ROOFLINE>> next).
//   +30-40 us, kernel APPEARS in top-5 -> writes throttled ~1.9 TB/s ->
//       read its real counters, attack the throttle.
//   +0-4 us -> probe skipped (small ws) or latency-bound w/ spare BW.

#define BS   256
#define M    64
#define C    1024
#define PAD  65   // 65 % 32 == 1 -> both LDS phases 2 lanes/bank = conflict-free

typedef float fx4 __attribute__((ext_vector_type(4)));

__global__ __launch_bounds__(256) void gather_transpose_kernel(
    const int* __restrict__ idx,      // [BS*M] int32
    const float* __restrict__ w,      // [NUM_EMB, C] fp32
    float* __restrict__ out,          // [BS, C, 8, 8] fp32
    float* __restrict__ ws,           // probe mirror (may be unused)
    int probe)
{
    const int b  = blockIdx.x >> 4;          // 16 channel-tiles per batch
    const int c0 = (blockIdx.x & 15) << 6;   // 64 channels per block

    __shared__ int   s_idx[M];
    __shared__ float tile[M * PAD];          // [cc][m], transposed

    const int t = threadIdx.x;
    if (t < M) s_idx[t] = idx[b * M + t];
    __syncthreads();

    // ---- load phase: gather rows, coalesced 256B per 16-lane group ----
    const int f = t & 15;                    // float4 index within the 64-ch slice
#pragma unroll
    for (int j = 0; j < 4; ++j) {
        const int m   = (t >> 4) + (j << 4); // token 0..63
        const int row = s_idx[m];
        const fx4 v = *(const fx4*)(w + row * C + c0 + (f << 2));
        tile[((f << 2) + 0) * PAD + m] = v.x;
        tile[((f << 2) + 1) * PAD + m] = v.y;
        tile[((f << 2) + 2) * PAD + m] = v.z;
        tile[((f << 2) + 3) * PAD + m] = v.w;
    }
    __syncthreads();

    // ---- store phase: 16 KiB contiguous per block, nt float4 ----
    const size_t off = ((size_t)(b * C + c0)) << 6;
    float* obase = out + off;
#pragma unroll
    for (int j = 0; j < 4; ++j) {
        const int fo = (j << 8) + t;         // float4 slot 0..1023
        const int cc = fo >> 4;              // channel within tile
        const int m  = (fo & 15) << 2;       // token group of 4
        fx4 v;
        v.x = tile[cc * PAD + m + 0];
        v.y = tile[cc * PAD + m + 1];
        v.z = tile[cc * PAD + m + 2];
        v.w = tile[cc * PAD + m + 3];
        __builtin_nontemporal_store(v, (fx4*)(obase + (cc << 6) + m));
    }

    // ---- probe: mirror the same 16 KiB into the workspace (disjoint) ----
    if (probe) {
        float* pbase = ws + off;
#pragma unroll
        for (int j = 0; j < 4; ++j) {
            const int fo = (j << 8) + t;
            const int cc = fo >> 4;
            const int m  = (fo & 15) << 2;
            fx4 v;
            v.x = tile[cc * PAD + m + 0];
            v.y = tile[cc * PAD + m + 1];
            v.z = tile[cc * PAD + m + 2];
            v.w = tile[cc * PAD + m + 3];
            __builtin_nontemporal_store(v, (fx4*)(pbase + (cc << 6) + m));
        }
    }
}

extern "C" void kernel_launch(void* const* d_in, const int* in_sizes, int n_in,
                              void* d_out, int out_size, void* d_ws, size_t ws_size,
                              hipStream_t stream) {
    const int*   idx = (const int*)d_in[0];    // encoding_indices [256, 64]
    const float* w   = (const float*)d_in[1];  // weight [1024, 1024]
    float*       out = (float*)d_out;          // [256, 1024, 8, 8]
    float*       ws  = (float*)d_ws;

    const size_t mirror_bytes = (size_t)BS * C * M * sizeof(float); // 64 MiB
    const int probe = (ws != nullptr && ws_size >= mirror_bytes) ? 1 : 0;

    dim3 grid(BS * (C / 64));  // 4096 blocks
    dim3 block(256);
    gather_transpose_kernel<<<grid, block, 0, stream>>>(idx, w, out, ws, probe);
}

// Round 6
// 79.708 us; speedup vs baseline: 1.1154x; 1.1154x over previous
//
#include <hip/hip_runtime.h>
#include <hip/hip_bf16.h>

// out[b, c, m] = weight[idx[b, m], c]   b<256, c<1024, m<64  (fp32, 64 MiB out)
//
// FINAL (roofline-verified): per-block 64x64 (m x c) LDS transpose.
//  - block = (batch b, 64-channel tile c0). grid = 256*16 = 4096.
//  - Load: quarter-wave (16 lanes) reads one gathered row's 256B contiguous
//    (float4) -> full cacheline utilization.
//  - LDS tile stored transposed [cc][m], PAD=65: both scalar phases are
//    2 lanes/bank = conflict-free (m136).
//  - Store: 16 KiB fully contiguous per block, non-temporal float4
//    (needs native vector type -> ext_vector_type).
//
// Roofline evidence (R4/R5 calibration probes):
//  - Disjoint-address 64 MiB write mirror into d_ws added exactly +9.05 us
//    (~7 TB/s marginal write BW) and the kernel never entered the rocprof
//    top-5 -> this kernel's own dispatch is ~13 us, i.e. at the HBM-write
//    floor (64 MiB / 6.3 TB/s ~= 11 us + latency tail).
//  - The remaining ~65 us of dur_us is harness: one 268 MB output re-poison
//    fill (~44 us @ 76% HBM peak) + ~20 us of tiny graph-serialized reset
//    dispatches. Not reachable from kernel source.
//  - Same-address double-store (R4) was +-0: gfx950 nt stores still
//    allocate in L2; same-line re-writes are absorbed. (Do not use
//    same-address double-writes as a BW probe.)
//  - Structure variants (2-barrier / nt / pipelined double-buffer) all
//    measured 79.9-83.0 us total: every variant sat on the same floor.

#define BS   256
#define M    64
#define C    1024
#define PAD  65   // 65 % 32 == 1 -> bank stride 1 for both access phases

typedef float fx4 __attribute__((ext_vector_type(4)));

__global__ __launch_bounds__(256) void gather_transpose_kernel(
    const int* __restrict__ idx,      // [BS*M] int32
    const float* __restrict__ w,      // [NUM_EMB, C] fp32
    float* __restrict__ out)          // [BS, C, 8, 8] fp32
{
    const int b  = blockIdx.x >> 4;          // 16 channel-tiles per batch
    const int c0 = (blockIdx.x & 15) << 6;   // 64 channels per block

    __shared__ int   s_idx[M];
    __shared__ float tile[M * PAD];          // [cc][m], transposed

    const int t = threadIdx.x;
    if (t < M) s_idx[t] = idx[b * M + t];
    __syncthreads();

    // ---- load phase: gather rows, coalesced 256B per 16-lane group ----
    const int f = t & 15;                    // float4 index within the 64-ch slice
#pragma unroll
    for (int j = 0; j < 4; ++j) {
        const int m   = (t >> 4) + (j << 4); // token 0..63
        const int row = s_idx[m];
        const fx4 v = *(const fx4*)(w + row * C + c0 + (f << 2));
        tile[((f << 2) + 0) * PAD + m] = v.x;
        tile[((f << 2) + 1) * PAD + m] = v.y;
        tile[((f << 2) + 2) * PAD + m] = v.z;
        tile[((f << 2) + 3) * PAD + m] = v.w;
    }
    __syncthreads();

    // ---- store phase: 16 KiB contiguous per block, nt float4 ----
    float* obase = out + (((size_t)(b * C + c0)) << 6);
#pragma unroll
    for (int j = 0; j < 4; ++j) {
        const int fo = (j << 8) + t;         // float4 slot 0..1023
        const int cc = fo >> 4;              // channel within tile
        const int m  = (fo & 15) << 2;       // token group of 4
        fx4 v;
        v.x = tile[cc * PAD + m + 0];
        v.y = tile[cc * PAD + m + 1];
        v.z = tile[cc * PAD + m + 2];
        v.w = tile[cc * PAD + m + 3];
        __builtin_nontemporal_store(v, (fx4*)(obase + (cc << 6) + m));
    }
}

extern "C" void kernel_launch(void* const* d_in, const int* in_sizes, int n_in,
                              void* d_out, int out_size, void* d_ws, size_t ws_size,
                              hipStream_t stream) {
    const int*   idx = (const int*)d_in[0];    // encoding_indices [256, 64]
    const float* w   = (const float*)d_in[1];  // weight [1024, 1024]
    float*       out = (float*)d_out;          // [256, 1024, 8, 8]

    dim3 grid(BS * (C / 64));  // 4096 blocks
    dim3 block(256);
    gather_transpose_kernel<<<grid, block, 0, stream>>>(idx, w, out);
}